// Round 9
// baseline (269.134 us; speedup 1.0000x reference)
//
#include <hip/hip_runtime.h>
#include <hip/hip_bf16.h>

#define D 8196
#define H 4096
#define MLP_HID 32
#define OUT_N 130
#define ND4 2049   // D/4 float4s per W_ih row
#define NH4 1024   // H/4 float4s per W_hh row

__device__ __forceinline__ float sigmoidf_(float v) {
    return 1.0f / (1.0f + expf(-v));
}

__device__ __forceinline__ float dot4(float4 a, float4 b) {
    return a.x * b.x + a.y * b.y + a.z * b.z + a.w * b.w;
}

__device__ __forceinline__ float wave_reduce(float acc) {
    #pragma unroll
    for (int off = 32; off > 0; off >>= 1)
        acc += __shfl_down(acc, off);
    return acc;
}

// 512 blocks x 512 threads (8 waves), 2 blocks/CU, single dispatch round.
// Block owns units j0..j0+7. Wave w: gate g=w&3, quad p=w>>2 -> 4 contiguous
// rows. x and h0 staged in LDS (49.2 KB); inner loops issue ONLY weight
// loads. Unroll 16 (vs 8) doubles outstanding loads per wave (Little's law:
// we were ~2KB in flight/CU vs ~9KB needed to saturate HBM latency).
__global__ __launch_bounds__(512, 4) void lstm_step_kernel(
    const float* __restrict__ x, const float* __restrict__ h0,
    const float* __restrict__ c0,
    const float* __restrict__ W_ih, const float* __restrict__ W_hh,
    const float* __restrict__ b_ih, const float* __restrict__ b_hh,
    float* __restrict__ h_out)
{
    __shared__ float4 xs[ND4];
    __shared__ float4 hs[NH4];
    __shared__ float gate[4][8];

    const int tid = threadIdx.x;
    {
        const float4* __restrict__ x4 = (const float4*)x;
        const float4* __restrict__ h4 = (const float4*)h0;
        for (int i = tid; i < ND4; i += 512) xs[i] = x4[i];
        for (int i = tid; i < NH4; i += 512) hs[i] = h4[i];
    }
    __syncthreads();

    const int w    = tid >> 6;   // wave 0..7
    const int lane = tid & 63;
    const int g    = w & 3;      // gate (i,f,g,o)
    const int p    = w >> 2;     // row quad 0/1
    const int j0   = blockIdx.x * 8;
    const int u0   = 4 * p;                      // first unit of this wave
    const size_t r0 = (size_t)g * H + j0 + u0;   // first of 4 contiguous rows

    float acc[4];

    // ---- W_ih rows r0..r0+3: one contiguous 131 KB stream ----
    {
        const float4* __restrict__ A = (const float4*)(W_ih + r0 * D);
        #pragma unroll
        for (int rr = 0; rr < 4; ++rr) {
            const float4* __restrict__ Ar = A + (size_t)rr * ND4;
            float a = 0.0f;
            #pragma unroll 16
            for (int it = 0; it < 32; ++it) {
                const int idx = it * 64 + lane;
                a += dot4(Ar[idx], xs[idx]);
            }
            if (lane == 0) a += dot4(Ar[2048], xs[2048]);
            acc[rr] = a;
        }
    }
    // ---- W_hh rows r0..r0+3: one contiguous 65.6 KB stream ----
    {
        const float4* __restrict__ B = (const float4*)(W_hh + r0 * H);
        #pragma unroll
        for (int rr = 0; rr < 4; ++rr) {
            const float4* __restrict__ Br = B + (size_t)rr * NH4;
            float a = acc[rr];
            #pragma unroll 16
            for (int it = 0; it < 16; ++it) {
                const int idx = it * 64 + lane;
                a += dot4(Br[idx], hs[idx]);
            }
            acc[rr] = a;
        }
    }

    #pragma unroll
    for (int rr = 0; rr < 4; ++rr) {
        const float a = wave_reduce(acc[rr]);
        if (lane == 0)
            gate[g][u0 + rr] = a + b_ih[r0 + rr] + b_hh[r0 + rr];
    }
    __syncthreads();

    if (tid < 8) {
        const int j = j0 + tid;
        const float ig = sigmoidf_(gate[0][tid]);
        const float fg = sigmoidf_(gate[1][tid]);
        const float gg = tanhf(gate[2][tid]);
        const float og = sigmoidf_(gate[3][tid]);
        const float c  = fg * c0[j] + ig * gg;
        h_out[j] = og * tanhf(c);
    }
}

// 32 blocks x 64 threads. Block r: z[r] = relu(W1[r,:]@h + b1[r]) -> global.
// Last finished block (atomic counter; only 32 fences, negligible) computes
// out = sigmoid(W2@z + b2) for all 130 outputs.
__global__ __launch_bounds__(64) void mlp_head_kernel(
    const float* __restrict__ h,
    const float* __restrict__ W1, const float* __restrict__ b1,
    const float* __restrict__ W2, const float* __restrict__ b2,
    float* __restrict__ z, unsigned int* __restrict__ counter,
    float* __restrict__ out)
{
    const int r    = blockIdx.x;
    const int lane = threadIdx.x;
    {
        const float4* __restrict__ Wr = (const float4*)(W1 + (size_t)r * H);
        const float4* __restrict__ h4 = (const float4*)h;
        float acc = 0.0f;
        #pragma unroll 4
        for (int it = 0; it < 16; ++it) {
            const int idx = it * 64 + lane;
            acc += dot4(Wr[idx], h4[idx]);
        }
        acc = wave_reduce(acc);
        if (lane == 0)
            z[r] = fmaxf(acc + b1[r], 0.0f);
    }

    __threadfence();
    __shared__ int lastflag;
    if (lane == 0)
        lastflag = (atomicAdd(counter, 1u) == (unsigned)(gridDim.x - 1));
    __syncthreads();
    if (!lastflag) return;
    __threadfence();  // acquire: see all blocks' z stores

    __shared__ float zs[MLP_HID];
    if (lane < MLP_HID) zs[lane] = z[lane];
    __syncthreads();

    #pragma unroll
    for (int t = lane; t < OUT_N; t += 64) {
        float acc = b2[t];
        #pragma unroll
        for (int k = 0; k < MLP_HID; ++k)
            acc += W2[t * MLP_HID + k] * zs[k];
        out[t] = sigmoidf_(acc);
    }
}

extern "C" void kernel_launch(void* const* d_in, const int* in_sizes, int n_in,
                              void* d_out, int out_size, void* d_ws, size_t ws_size,
                              hipStream_t stream) {
    const float* x    = (const float*)d_in[0];
    const float* h0   = (const float*)d_in[1];
    const float* c0   = (const float*)d_in[2];
    const float* W_ih = (const float*)d_in[3];
    const float* W_hh = (const float*)d_in[4];
    const float* b_ih = (const float*)d_in[5];
    const float* b_hh = (const float*)d_in[6];
    const float* W1   = (const float*)d_in[7];
    const float* b1   = (const float*)d_in[8];
    const float* W2   = (const float*)d_in[9];
    const float* b2   = (const float*)d_in[10];
    float* out = (float*)d_out;

    // ws layout: [0,16KB) h | [16KB, +128B) z | [16KB+256B, +4B) counter
    float* h_ws = (float*)d_ws;
    float* z_ws = (float*)((char*)d_ws + 16384);
    unsigned int* counter = (unsigned int*)((char*)d_ws + 16384 + 256);

    (void)hipMemsetAsync(counter, 0, sizeof(unsigned int), stream);
    lstm_step_kernel<<<H / 8, 512, 0, stream>>>(x, h0, c0, W_ih, W_hh, b_ih, b_hh, h_ws);
    mlp_head_kernel<<<MLP_HID, 64, 0, stream>>>(h_ws, W1, b1, W2, b2, z_ws, counter, out);
}

// Round 10
// 155.220 us; speedup vs baseline: 1.7339x; 1.7339x over previous
//
#include <hip/hip_runtime.h>
#include <hip/hip_bf16.h>

#define D 8196
#define H 4096
#define MLP_HID 32
#define OUT_N 130
#define ND4 2049   // D/4 float4s per W_ih row
#define NH4 1024   // H/4 float4s per W_hh row

__device__ __forceinline__ float sigmoidf_(float v) {
    return 1.0f / (1.0f + expf(-v));
}

__device__ __forceinline__ float dot4(float4 a, float4 b) {
    return a.x * b.x + a.y * b.y + a.z * b.z + a.w * b.w;
}

__device__ __forceinline__ float wave_reduce(float acc) {
    #pragma unroll
    for (int off = 32; off > 0; off >>= 1)
        acc += __shfl_down(acc, off);
    return acc;
}

// 512 blocks x 512 threads (8 waves), 2 blocks/CU, single dispatch round.
// Block owns units j0..j0+7. Wave w: gate g=w&3, quad p=w>>2 -> 4 contiguous
// rows. x and h0 staged in LDS (49.2 KB); inner loops issue ONLY weight
// loads. Unroll 8 — unroll 16 (R9) blew the 128-VGPR budget (spill/serialize,
// 149 -> 269 us). Do not raise.
__global__ __launch_bounds__(512, 4) void lstm_step_kernel(
    const float* __restrict__ x, const float* __restrict__ h0,
    const float* __restrict__ c0,
    const float* __restrict__ W_ih, const float* __restrict__ W_hh,
    const float* __restrict__ b_ih, const float* __restrict__ b_hh,
    float* __restrict__ h_out)
{
    __shared__ float4 xs[ND4];
    __shared__ float4 hs[NH4];
    __shared__ float gate[4][8];

    const int tid = threadIdx.x;
    {
        const float4* __restrict__ x4 = (const float4*)x;
        const float4* __restrict__ h4 = (const float4*)h0;
        for (int i = tid; i < ND4; i += 512) xs[i] = x4[i];
        for (int i = tid; i < NH4; i += 512) hs[i] = h4[i];
    }
    __syncthreads();

    const int w    = tid >> 6;   // wave 0..7
    const int lane = tid & 63;
    const int g    = w & 3;      // gate (i,f,g,o)
    const int p    = w >> 2;     // row quad 0/1
    const int j0   = blockIdx.x * 8;
    const int u0   = 4 * p;                      // first unit of this wave
    const size_t r0 = (size_t)g * H + j0 + u0;   // first of 4 contiguous rows

    float acc[4];

    // ---- W_ih rows r0..r0+3: one contiguous 131 KB stream ----
    {
        const float4* __restrict__ A = (const float4*)(W_ih + r0 * D);
        #pragma unroll
        for (int rr = 0; rr < 4; ++rr) {
            const float4* __restrict__ Ar = A + (size_t)rr * ND4;
            float a = 0.0f;
            #pragma unroll 8
            for (int it = 0; it < 32; ++it) {
                const int idx = it * 64 + lane;
                a += dot4(Ar[idx], xs[idx]);
            }
            if (lane == 0) a += dot4(Ar[2048], xs[2048]);
            acc[rr] = a;
        }
    }
    // ---- W_hh rows r0..r0+3: one contiguous 65.6 KB stream ----
    {
        const float4* __restrict__ B = (const float4*)(W_hh + r0 * H);
        #pragma unroll
        for (int rr = 0; rr < 4; ++rr) {
            const float4* __restrict__ Br = B + (size_t)rr * NH4;
            float a = acc[rr];
            #pragma unroll 8
            for (int it = 0; it < 16; ++it) {
                const int idx = it * 64 + lane;
                a += dot4(Br[idx], hs[idx]);
            }
            acc[rr] = a;
        }
    }

    #pragma unroll
    for (int rr = 0; rr < 4; ++rr) {
        const float a = wave_reduce(acc[rr]);
        if (lane == 0)
            gate[g][u0 + rr] = a + b_ih[r0 + rr] + b_hh[r0 + rr];
    }
    __syncthreads();

    if (tid < 8) {
        const int j = j0 + tid;
        const float ig = sigmoidf_(gate[0][tid]);
        const float fg = sigmoidf_(gate[1][tid]);
        const float gg = tanhf(gate[2][tid]);
        const float og = sigmoidf_(gate[3][tid]);
        const float c  = fg * c0[j] + ig * gg;
        h_out[j] = og * tanhf(c);
    }
}

// 32 blocks x 64 threads. Block r: z[r] = relu(W1[r,:]@h + b1[r]) -> global.
// Last finished block (atomic counter; only 32 fences, negligible) computes
// out = sigmoid(W2@z + b2) for all 130 outputs.
__global__ __launch_bounds__(64) void mlp_head_kernel(
    const float* __restrict__ h,
    const float* __restrict__ W1, const float* __restrict__ b1,
    const float* __restrict__ W2, const float* __restrict__ b2,
    float* __restrict__ z, unsigned int* __restrict__ counter,
    float* __restrict__ out)
{
    const int r    = blockIdx.x;
    const int lane = threadIdx.x;
    {
        const float4* __restrict__ Wr = (const float4*)(W1 + (size_t)r * H);
        const float4* __restrict__ h4 = (const float4*)h;
        float acc = 0.0f;
        #pragma unroll 4
        for (int it = 0; it < 16; ++it) {
            const int idx = it * 64 + lane;
            acc += dot4(Wr[idx], h4[idx]);
        }
        acc = wave_reduce(acc);
        if (lane == 0)
            z[r] = fmaxf(acc + b1[r], 0.0f);
    }

    __threadfence();
    __shared__ int lastflag;
    if (lane == 0)
        lastflag = (atomicAdd(counter, 1u) == (unsigned)(gridDim.x - 1));
    __syncthreads();
    if (!lastflag) return;
    __threadfence();  // acquire: see all blocks' z stores

    __shared__ float zs[MLP_HID];
    if (lane < MLP_HID) zs[lane] = z[lane];
    __syncthreads();

    #pragma unroll
    for (int t = lane; t < OUT_N; t += 64) {
        float acc = b2[t];
        #pragma unroll
        for (int k = 0; k < MLP_HID; ++k)
            acc += W2[t * MLP_HID + k] * zs[k];
        out[t] = sigmoidf_(acc);
    }
}

extern "C" void kernel_launch(void* const* d_in, const int* in_sizes, int n_in,
                              void* d_out, int out_size, void* d_ws, size_t ws_size,
                              hipStream_t stream) {
    const float* x    = (const float*)d_in[0];
    const float* h0   = (const float*)d_in[1];
    const float* c0   = (const float*)d_in[2];
    const float* W_ih = (const float*)d_in[3];
    const float* W_hh = (const float*)d_in[4];
    const float* b_ih = (const float*)d_in[5];
    const float* b_hh = (const float*)d_in[6];
    const float* W1   = (const float*)d_in[7];
    const float* b1   = (const float*)d_in[8];
    const float* W2   = (const float*)d_in[9];
    const float* b2   = (const float*)d_in[10];
    float* out = (float*)d_out;

    // ws layout: [0,16KB) h | [16KB, +128B) z | [16KB+256B, +4B) counter
    float* h_ws = (float*)d_ws;
    float* z_ws = (float*)((char*)d_ws + 16384);
    unsigned int* counter = (unsigned int*)((char*)d_ws + 16384 + 256);

    (void)hipMemsetAsync(counter, 0, sizeof(unsigned int), stream);
    lstm_step_kernel<<<H / 8, 512, 0, stream>>>(x, h0, c0, W_ih, W_hh, b_ih, b_hh, h_ws);
    mlp_head_kernel<<<MLP_HID, 64, 0, stream>>>(h_ws, W1, b1, W2, b2, z_ws, counter, out);
}

// Round 11
// 153.723 us; speedup vs baseline: 1.7508x; 1.0097x over previous
//
#include <hip/hip_runtime.h>
#include <hip/hip_bf16.h>

#define D 8196
#define H 4096
#define MLP_HID 32
#define OUT_N 130
#define ND4 2049   // D/4 float4s per W_ih row
#define NH4 1024   // H/4 float4s per W_hh row

__device__ __forceinline__ float sigmoidf_(float v) {
    return 1.0f / (1.0f + expf(-v));
}

__device__ __forceinline__ float dot4(float4 a, float4 b) {
    return a.x * b.x + a.y * b.y + a.z * b.z + a.w * b.w;
}

__device__ __forceinline__ float wave_reduce(float acc) {
    #pragma unroll
    for (int off = 32; off > 0; off >>= 1)
        acc += __shfl_down(acc, off);
    return acc;
}

// 512 blocks x 512 threads (8 waves), 2 blocks/CU, single dispatch round.
// Block owns units j0..j0+7. Wave w: gate g=w&3, quad p=w>>2 -> 4 contiguous
// rows. x and h0 staged in LDS (49.2 KB); inner loops issue ONLY weight
// loads, unroll 8 (unroll 16 blew the 128-VGPR budget: 149 -> 269 us).
// Tail fold: after computing its 8 h-values, the block adds the rank-8
// partial W1[:, j0..j0+7] @ h_local into z_ws via device-scope atomicAdd —
// eliminates the separate 32-block mlp_z kernel; kernel-boundary ordering
// makes mlp_out safe with no fences.
__global__ __launch_bounds__(512, 4) void lstm_step_kernel(
    const float* __restrict__ x, const float* __restrict__ h0,
    const float* __restrict__ c0,
    const float* __restrict__ W_ih, const float* __restrict__ W_hh,
    const float* __restrict__ b_ih, const float* __restrict__ b_hh,
    const float* __restrict__ W1,
    float* __restrict__ z_ws)
{
    __shared__ float4 xs[ND4];
    __shared__ float4 hs[NH4];
    __shared__ float gate[4][8];
    __shared__ float hloc[8];

    const int tid = threadIdx.x;
    {
        const float4* __restrict__ x4 = (const float4*)x;
        const float4* __restrict__ h4 = (const float4*)h0;
        for (int i = tid; i < ND4; i += 512) xs[i] = x4[i];
        for (int i = tid; i < NH4; i += 512) hs[i] = h4[i];
    }
    __syncthreads();

    const int w    = tid >> 6;   // wave 0..7
    const int lane = tid & 63;
    const int g    = w & 3;      // gate (i,f,g,o)
    const int p    = w >> 2;     // row quad 0/1
    const int j0   = blockIdx.x * 8;
    const int u0   = 4 * p;                      // first unit of this wave
    const size_t r0 = (size_t)g * H + j0 + u0;   // first of 4 contiguous rows

    float acc[4];

    // ---- W_ih rows r0..r0+3: one contiguous 131 KB stream ----
    {
        const float4* __restrict__ A = (const float4*)(W_ih + r0 * D);
        #pragma unroll
        for (int rr = 0; rr < 4; ++rr) {
            const float4* __restrict__ Ar = A + (size_t)rr * ND4;
            float a = 0.0f;
            #pragma unroll 8
            for (int it = 0; it < 32; ++it) {
                const int idx = it * 64 + lane;
                a += dot4(Ar[idx], xs[idx]);
            }
            if (lane == 0) a += dot4(Ar[2048], xs[2048]);
            acc[rr] = a;
        }
    }
    // ---- W_hh rows r0..r0+3: one contiguous 65.6 KB stream ----
    {
        const float4* __restrict__ B = (const float4*)(W_hh + r0 * H);
        #pragma unroll
        for (int rr = 0; rr < 4; ++rr) {
            const float4* __restrict__ Br = B + (size_t)rr * NH4;
            float a = acc[rr];
            #pragma unroll 8
            for (int it = 0; it < 16; ++it) {
                const int idx = it * 64 + lane;
                a += dot4(Br[idx], hs[idx]);
            }
            acc[rr] = a;
        }
    }

    #pragma unroll
    for (int rr = 0; rr < 4; ++rr) {
        const float a = wave_reduce(acc[rr]);
        if (lane == 0)
            gate[g][u0 + rr] = a + b_ih[r0 + rr] + b_hh[r0 + rr];
    }
    __syncthreads();

    if (tid < 8) {
        const int j = j0 + tid;
        const float ig = sigmoidf_(gate[0][tid]);
        const float fg = sigmoidf_(gate[1][tid]);
        const float gg = tanhf(gate[2][tid]);
        const float og = sigmoidf_(gate[3][tid]);
        const float c  = fg * c0[j] + ig * gg;
        hloc[tid] = og * tanhf(c);
    }
    __syncthreads();

    // rank-8 partial of z = W1 @ h: thread r (0..31) handles row r.
    if (tid < MLP_HID) {
        const float* __restrict__ Wr = W1 + (size_t)tid * H + j0;
        float a = 0.0f;
        #pragma unroll
        for (int j = 0; j < 8; ++j)
            a += Wr[j] * hloc[j];
        atomicAdd(&z_ws[tid], a);
    }
}

// 1 block: out = sigmoid(W2 @ relu(z + b1) + b2), 130 outputs.
// Runs after lstm_step_kernel (stream order) -> z_ws complete, no fence needed.
__global__ __launch_bounds__(192) void mlp_out_kernel(
    const float* __restrict__ z,
    const float* __restrict__ b1,
    const float* __restrict__ W2, const float* __restrict__ b2,
    float* __restrict__ out)
{
    __shared__ float zs[MLP_HID];
    if (threadIdx.x < MLP_HID)
        zs[threadIdx.x] = fmaxf(z[threadIdx.x] + b1[threadIdx.x], 0.0f);
    __syncthreads();
    const int t = threadIdx.x;
    if (t < OUT_N) {
        float acc = b2[t];
        #pragma unroll
        for (int k = 0; k < MLP_HID; ++k)
            acc += W2[t * MLP_HID + k] * zs[k];
        out[t] = sigmoidf_(acc);
    }
}

extern "C" void kernel_launch(void* const* d_in, const int* in_sizes, int n_in,
                              void* d_out, int out_size, void* d_ws, size_t ws_size,
                              hipStream_t stream) {
    const float* x    = (const float*)d_in[0];
    const float* h0   = (const float*)d_in[1];
    const float* c0   = (const float*)d_in[2];
    const float* W_ih = (const float*)d_in[3];
    const float* W_hh = (const float*)d_in[4];
    const float* b_ih = (const float*)d_in[5];
    const float* b_hh = (const float*)d_in[6];
    const float* W1   = (const float*)d_in[7];
    const float* b1   = (const float*)d_in[8];
    const float* W2   = (const float*)d_in[9];
    const float* b2   = (const float*)d_in[10];
    float* out = (float*)d_out;

    float* z_ws = (float*)d_ws;  // MLP_HID floats, accumulated via atomicAdd

    (void)hipMemsetAsync(z_ws, 0, MLP_HID * sizeof(float), stream);
    lstm_step_kernel<<<H / 8, 512, 0, stream>>>(x, h0, c0, W_ih, W_hh,
                                                b_ih, b_hh, W1, z_ws);
    mlp_out_kernel<<<1, 192, 0, stream>>>(z_ws, b1, W2, b2, out);
}

// Round 12
// 148.979 us; speedup vs baseline: 1.8065x; 1.0318x over previous
//
#include <hip/hip_runtime.h>
#include <hip/hip_bf16.h>

#define D 8196
#define H 4096
#define MLP_HID 32
#define OUT_N 130
#define ND4 2049   // D/4 float4s per W_ih row
#define NH4 1024   // H/4 float4s per W_hh row

__device__ __forceinline__ float sigmoidf_(float v) {
    return 1.0f / (1.0f + expf(-v));
}

__device__ __forceinline__ float dot4(float4 a, float4 b) {
    return a.x * b.x + a.y * b.y + a.z * b.z + a.w * b.w;
}

__device__ __forceinline__ float wave_reduce(float acc) {
    #pragma unroll
    for (int off = 32; off > 0; off >>= 1)
        acc += __shfl_down(acc, off);
    return acc;
}

// R8 config (best measured: 149.1 us). 512 blocks x 512 threads (8 waves),
// 2 blocks/CU, single dispatch round. Block owns units j0..j0+7. Wave w:
// gate g=w&3, quad p=w>>2 -> 4 contiguous rows. x and h0 staged in LDS
// (49.2 KB); inner loops issue ONLY weight loads, unroll 8 (16 blows the
// 128-VGPR budget: 269 us). Plain 3-kernel tail: every fused/atomic variant
// (R9/R10/R11) was 4-6 us slower than kernel-boundary ordering.
__global__ __launch_bounds__(512, 4) void lstm_step_kernel(
    const float* __restrict__ x, const float* __restrict__ h0,
    const float* __restrict__ c0,
    const float* __restrict__ W_ih, const float* __restrict__ W_hh,
    const float* __restrict__ b_ih, const float* __restrict__ b_hh,
    float* __restrict__ h_out)
{
    __shared__ float4 xs[ND4];
    __shared__ float4 hs[NH4];
    __shared__ float gate[4][8];

    const int tid = threadIdx.x;
    {
        const float4* __restrict__ x4 = (const float4*)x;
        const float4* __restrict__ h4 = (const float4*)h0;
        for (int i = tid; i < ND4; i += 512) xs[i] = x4[i];
        for (int i = tid; i < NH4; i += 512) hs[i] = h4[i];
    }
    __syncthreads();

    const int w    = tid >> 6;   // wave 0..7
    const int lane = tid & 63;
    const int g    = w & 3;      // gate (i,f,g,o)
    const int p    = w >> 2;     // row quad 0/1
    const int j0   = blockIdx.x * 8;
    const int u0   = 4 * p;                      // first unit of this wave
    const size_t r0 = (size_t)g * H + j0 + u0;   // first of 4 contiguous rows

    float acc[4];

    // ---- W_ih rows r0..r0+3: one contiguous 131 KB stream ----
    {
        const float4* __restrict__ A = (const float4*)(W_ih + r0 * D);
        #pragma unroll
        for (int rr = 0; rr < 4; ++rr) {
            const float4* __restrict__ Ar = A + (size_t)rr * ND4;
            float a = 0.0f;
            #pragma unroll 8
            for (int it = 0; it < 32; ++it) {
                const int idx = it * 64 + lane;
                a += dot4(Ar[idx], xs[idx]);
            }
            if (lane == 0) a += dot4(Ar[2048], xs[2048]);
            acc[rr] = a;
        }
    }
    // ---- W_hh rows r0..r0+3: one contiguous 65.6 KB stream ----
    {
        const float4* __restrict__ B = (const float4*)(W_hh + r0 * H);
        #pragma unroll
        for (int rr = 0; rr < 4; ++rr) {
            const float4* __restrict__ Br = B + (size_t)rr * NH4;
            float a = acc[rr];
            #pragma unroll 8
            for (int it = 0; it < 16; ++it) {
                const int idx = it * 64 + lane;
                a += dot4(Br[idx], hs[idx]);
            }
            acc[rr] = a;
        }
    }

    #pragma unroll
    for (int rr = 0; rr < 4; ++rr) {
        const float a = wave_reduce(acc[rr]);
        if (lane == 0)
            gate[g][u0 + rr] = a + b_ih[r0 + rr] + b_hh[r0 + rr];
    }
    __syncthreads();

    if (tid < 8) {
        const int j = j0 + tid;
        const float ig = sigmoidf_(gate[0][tid]);
        const float fg = sigmoidf_(gate[1][tid]);
        const float gg = tanhf(gate[2][tid]);
        const float og = sigmoidf_(gate[3][tid]);
        const float c  = fg * c0[j] + ig * gg;
        h_out[j] = og * tanhf(c);
    }
}

// 32 blocks x 64 threads: block r computes z[r] = relu(W1[r,:] @ h + b1[r])
__global__ __launch_bounds__(64) void mlp_z_kernel(
    const float* __restrict__ h,
    const float* __restrict__ W1, const float* __restrict__ b1,
    float* __restrict__ z)
{
    const int r    = blockIdx.x;
    const int lane = threadIdx.x;
    const float4* __restrict__ Wr = (const float4*)(W1 + (size_t)r * H);
    const float4* __restrict__ h4 = (const float4*)h;
    float acc = 0.0f;
    #pragma unroll 4
    for (int it = 0; it < 16; ++it) {
        const int idx = it * 64 + lane;
        acc += dot4(Wr[idx], h4[idx]);
    }
    acc = wave_reduce(acc);
    if (lane == 0)
        z[r] = fmaxf(acc + b1[r], 0.0f);
}

// 1 block: out = sigmoid(W2 @ z + b2), 130 outputs
__global__ __launch_bounds__(192) void mlp_out_kernel(
    const float* __restrict__ z,
    const float* __restrict__ W2, const float* __restrict__ b2,
    float* __restrict__ out)
{
    __shared__ float zs[MLP_HID];
    if (threadIdx.x < MLP_HID) zs[threadIdx.x] = z[threadIdx.x];
    __syncthreads();
    const int t = threadIdx.x;
    if (t < OUT_N) {
        float acc = b2[t];
        #pragma unroll
        for (int k = 0; k < MLP_HID; ++k)
            acc += W2[t * MLP_HID + k] * zs[k];
        out[t] = sigmoidf_(acc);
    }
}

extern "C" void kernel_launch(void* const* d_in, const int* in_sizes, int n_in,
                              void* d_out, int out_size, void* d_ws, size_t ws_size,
                              hipStream_t stream) {
    const float* x    = (const float*)d_in[0];
    const float* h0   = (const float*)d_in[1];
    const float* c0   = (const float*)d_in[2];
    const float* W_ih = (const float*)d_in[3];
    const float* W_hh = (const float*)d_in[4];
    const float* b_ih = (const float*)d_in[5];
    const float* b_hh = (const float*)d_in[6];
    const float* W1   = (const float*)d_in[7];
    const float* b1   = (const float*)d_in[8];
    const float* W2   = (const float*)d_in[9];
    const float* b2   = (const float*)d_in[10];
    float* out = (float*)d_out;

    // ws layout: [0, 16KB) h, [16KB, 16KB+128) z
    float* h_ws = (float*)d_ws;
    float* z_ws = (float*)((char*)d_ws + 16384);

    lstm_step_kernel<<<H / 8, 512, 0, stream>>>(x, h0, c0, W_ih, W_hh, b_ih, b_hh, h_ws);
    mlp_z_kernel<<<MLP_HID, 64, 0, stream>>>(h_ws, W1, b1, z_ws);
    mlp_out_kernel<<<1, 192, 0, stream>>>(z_ws, W2, b2, out);
}